// Round 15
// baseline (256.614 us; speedup 1.0000x reference)
//
#include <hip/hip_runtime.h>

#define N_NODES 59392
#define N_EDGES 1187840
#define F_IN 116
#define F_HID 64
#define BATCH 512
#define NPG 116              // nodes per graph
#define CCAP 64              // bucket: 64 u16 = one 128B line/node; P(indeg>64)~1e-15, guarded
#define NSLD 160             // dst-hist / place slices
#define EPSD (N_EDGES / NSLD)  // 7424 edges per dst-slice (exact)
#define NSLS 64              // src-hist slices
#define EPSS (N_EDGES / NSLS)  // 18560 edges per src-slice (exact)
#define NR 4                 // node ranges
#define NPR4 (N_NODES / NR)  // 14848 nodes per range (exact)
#define GPB 4                // readout blocks per graph
#define NPB (NPG / GPB)      // 29 nodes per readout block (exact)
#define SCAN_BLK (N_NODES / 256)   // 232
#define GEMM_BLK 640

typedef __attribute__((ext_vector_type(8))) short short8;
typedef __attribute__((ext_vector_type(4))) float float4v;

__device__ __forceinline__ float u2f(unsigned u) {
    union { unsigned u; float f; } x; x.u = u; return x.f;
}
__device__ __forceinline__ float bf2f(unsigned short h) {
    union { unsigned u; float f; } x; x.u = (unsigned)h << 16; return x.f;
}
__device__ __forceinline__ unsigned short f2bf(float f) {
    union { float f; unsigned u; } x; x.f = f;
    unsigned r = x.u + 0x7FFF + ((x.u >> 16) & 1);   // RNE
    return (unsigned short)(r >> 16);
}

// ---------------------------------------------------------------- 1) histograms: 896 blocks, 29.7KB packed-u16 LDS bins
__global__ __launch_bounds__(256) void hist_kernel(const int* __restrict__ src,
                                                   const int* __restrict__ dst,
                                                   unsigned short* __restrict__ cnt2,
                                                   unsigned short* __restrict__ cnt2s) {
    __shared__ unsigned bins[NPR4 / 2];   // 29696 B
    int tid = threadIdx.x;
    int b = blockIdx.x;
    const int* __restrict__ idx;
    unsigned short* outp;
    int slice, range, nedge;
    if (b < NSLD * NR) {
        slice = b >> 2; range = b & 3; idx = dst; outp = cnt2; nedge = EPSD;
    } else {
        int bb = b - NSLD * NR;
        slice = bb >> 2; range = bb & 3; idx = src; outp = cnt2s; nedge = EPSS;
    }
    int r0 = range * NPR4;
    long ebase = (long)slice * nedge;
    for (int k = tid; k < NPR4 / 2; k += 256) bins[k] = 0;
    __syncthreads();
    for (int k = tid; k < nedge; k += 256) {
        int v = idx[ebase + k] - r0;
        if ((unsigned)v < NPR4) atomicAdd(&bins[v >> 1], 1u << ((v & 1) * 16));
    }
    __syncthreads();
    unsigned* op = (unsigned*)(outp + (size_t)slice * N_NODES + r0);
    for (int k = tid; k < NPR4 / 2; k += 256) op[k] = bins[k];
}

// ---------------------------------------------------------------- 2) FUSED: scan+norms (blocks 0..231) | gemm1 MFMA (blocks 232..871)
__global__ __launch_bounds__(256) void scan_gemm1_kernel(unsigned short* __restrict__ cnt2,
                                                         const unsigned short* __restrict__ cnt2s,
                                                         float* __restrict__ onorm,
                                                         float* __restrict__ inorm,
                                                         int* __restrict__ ncnt,
                                                         const float* __restrict__ feat,
                                                         const float* __restrict__ W1,
                                                         unsigned short* __restrict__ A1lo,
                                                         unsigned short* __restrict__ A1hi) {
    if (blockIdx.x < SCAN_BLK) {
        // ---- scan role: 8-wide batched loads
        int d = blockIdx.x * 256 + threadIdx.x;
        int run = 0;
        #pragma unroll 1
        for (int i = 0; i < NSLD; i += 8) {
            int c[8];
            #pragma unroll
            for (int j = 0; j < 8; ++j) c[j] = cnt2[(size_t)(i + j) * N_NODES + d];
            #pragma unroll
            for (int j = 0; j < 8; ++j) {
                cnt2[(size_t)(i + j) * N_NODES + d] = (unsigned short)run;
                run += c[j];
            }
        }
        int o = 0;
        #pragma unroll 1
        for (int i = 0; i < NSLS; i += 8) {
            int c[8];
            #pragma unroll
            for (int j = 0; j < 8; ++j) c[j] = cnt2s[(size_t)(i + j) * N_NODES + d];
            #pragma unroll
            for (int j = 0; j < 8; ++j) o += c[j];
        }
        onorm[d] = rsqrtf(fmaxf((float)o, 1.0f));
        inorm[d] = rsqrtf(fmaxf((float)run, 1.0f));
        ncnt[d] = run < CCAP ? run : CCAP;
        if (d == 0) onorm[N_NODES] = 0.f;         // zero-row kill switch (gather1)
        return;
    }
    // ---- gemm1 role: A1 = feat @ W1 (bf16 out, hi/lo split = fp32-exact), feature-split arrays
    int lane = threadIdx.x & 63;
    int c16 = lane & 15, quad = lane >> 4;
    short8 Bhi[4][4], Blo[4][4];
    #pragma unroll
    for (int kiter = 0; kiter < 4; ++kiter) {
        #pragma unroll
        for (int t = 0; t < 4; ++t) {
            #pragma unroll
            for (int j = 0; j < 8; ++j) {
                int k = kiter * 32 + quad * 8 + j;
                float w = (k < F_IN) ? W1[k * F_HID + t * 16 + c16] : 0.f;
                unsigned short hi = f2bf(w);
                unsigned short lo = f2bf(w - bf2f(hi));
                Bhi[kiter][t][j] = (short)hi;
                Blo[kiter][t][j] = (short)lo;
            }
        }
    }
    int bid = blockIdx.x - SCAN_BLK;
    int wid = (bid * 256 + threadIdx.x) >> 6;
    int nwaves = (GEMM_BLK * 256) >> 6;
    const int ntiles = N_NODES / 16;   // 3712
    for (int tile = wid; tile < ntiles; tile += nwaves) {
        int base = tile * 16;
        int row = base + c16;
        const float* fp = feat + (size_t)row * F_IN;
        float4v acc[4] = {{0.f,0.f,0.f,0.f},{0.f,0.f,0.f,0.f},{0.f,0.f,0.f,0.f},{0.f,0.f,0.f,0.f}};
        #pragma unroll
        for (int kiter = 0; kiter < 4; ++kiter) {
            int koff = kiter * 32 + quad * 8;
            float f[8];
            if (koff + 8 <= F_IN) {
                float4 x = *(const float4*)(fp + koff);
                float4 y = *(const float4*)(fp + koff + 4);
                f[0]=x.x; f[1]=x.y; f[2]=x.z; f[3]=x.w;
                f[4]=y.x; f[5]=y.y; f[6]=y.z; f[7]=y.w;
            } else {
                #pragma unroll
                for (int j = 0; j < 8; ++j) f[j] = (koff + j < F_IN) ? fp[koff + j] : 0.f;
            }
            short8 ah, al;
            #pragma unroll
            for (int j = 0; j < 8; ++j) {
                float v = f[j];
                unsigned short hi = f2bf(v);
                ah[j] = (short)hi;
                al[j] = (short)f2bf(v - bf2f(hi));
            }
            #pragma unroll
            for (int t = 0; t < 4; ++t) {
                acc[t] = __builtin_amdgcn_mfma_f32_16x16x32_bf16(ah, Bhi[kiter][t], acc[t], 0, 0, 0);
                acc[t] = __builtin_amdgcn_mfma_f32_16x16x32_bf16(al, Bhi[kiter][t], acc[t], 0, 0, 0);
                acc[t] = __builtin_amdgcn_mfma_f32_16x16x32_bf16(ah, Blo[kiter][t], acc[t], 0, 0, 0);
            }
        }
        #pragma unroll
        for (int t = 0; t < 4; ++t) {
            unsigned short* outp = (t < 2) ? A1lo : A1hi;
            int fo = (t & 1) * 16 + c16;
            #pragma unroll
            for (int r = 0; r < 4; ++r) {
                int node = base + quad * 4 + r;
                outp[(size_t)node * 32 + fo] = f2bf(acc[t][r]);
            }
        }
    }
}

// ---------------------------------------------------------------- 3) placement: 640 blocks, packed cursors, unroll-4
__global__ __launch_bounds__(256) void place_kernel(const int* __restrict__ src,
                                                    const int* __restrict__ dst,
                                                    const unsigned short* __restrict__ cnt2,
                                                    unsigned short* __restrict__ ebuf) {
    __shared__ unsigned cur[NPR4 / 2];    // 29696 B
    int tid = threadIdx.x;
    int slice = blockIdx.x >> 2;
    int r0 = (blockIdx.x & 3) * NPR4;
    long ebase = (long)slice * EPSD;
    const unsigned* pp = (const unsigned*)(cnt2 + (size_t)slice * N_NODES + r0);
    for (int k = tid; k < NPR4 / 2; k += 256) cur[k] = pp[k];
    __syncthreads();
    #pragma unroll 1
    for (int t = 0; t < 7; ++t) {
        int k = t * 1024 + tid;
        int d0 = dst[ebase + k],        s0 = src[ebase + k];
        int d1 = dst[ebase + k + 256],  s1 = src[ebase + k + 256];
        int d2 = dst[ebase + k + 512],  s2 = src[ebase + k + 512];
        int d3 = dst[ebase + k + 768],  s3 = src[ebase + k + 768];
        #define PLACE1(dd, ss)                                                    \
            { int dr = (dd) - r0;                                                 \
              if ((unsigned)dr < NPR4) {                                          \
                  int sh = (dr & 1) * 16;                                         \
                  unsigned old = atomicAdd(&cur[dr >> 1], 1u << sh);              \
                  unsigned pos = (old >> sh) & 0xFFFFu;                           \
                  if (pos < CCAP) ebuf[(size_t)(dd) * CCAP + pos] = (unsigned short)(ss); } }
        PLACE1(d0, s0) PLACE1(d1, s1) PLACE1(d2, s2) PLACE1(d3, s3)
    }
    {   // tail: edges [7168, 7424)
        int k = 7168 + tid;
        int d0 = dst[ebase + k], s0 = src[ebase + k];
        PLACE1(d0, s0)
        #undef PLACE1
    }
}

// ---------------------------------------------------------------- gather core: HALF-ROW (64B), 8 edges per wave-load, 2 nodes
// base = half-array (rows of 32 bf16 = 16 u32). Lane: c8 = lane&7 (feature quad),
// g8 = lane>>3 (edge slot). Invalid slots -> row N_NODES (onorm=0 / zeroed row).
// ebuf/index loads are NONTEMPORAL so the streaming data doesn't evict the
// 3.8MB half-array from the XCD L2 (the point of the split).
template<bool ON>
__device__ __forceinline__ void gath2(const unsigned* __restrict__ base,
                                      const unsigned short* __restrict__ ebuf,
                                      const float* __restrict__ onorm,
                                      int va, int vb, int na, int nb,
                                      int c8, int g8,
                                      float* __restrict__ A, float* __restrict__ B) {
    const unsigned long long* ea = (const unsigned long long*)(ebuf + (size_t)va * CCAP);
    const unsigned long long* eb = (const unsigned long long*)(ebuf + (size_t)vb * CCAP);
    int qi = g8 >> 2;            // which u64 of the chunk pair
    int sh = (g8 & 3) * 16;
    unsigned long long cha[4], chb[4];
    #pragma unroll
    for (int t = 0; t < 4; ++t) {
        cha[t] = __builtin_nontemporal_load(&ea[2 * t + qi]);
        chb[t] = __builtin_nontemporal_load(&eb[2 * t + qi]);
    }
    int ida[4], idb[4];
    #pragma unroll
    for (int t = 0; t < 4; ++t) {
        ida[t] = (t * 8 + g8 < na) ? (int)((cha[t] >> sh) & 0xFFFFu) : N_NODES;
        idb[t] = (t * 8 + g8 < nb) ? (int)((chb[t] >> sh) & 0xFFFFu) : N_NODES;
    }
    unsigned long long rwa[4], rwb[4];
    #pragma unroll
    for (int t = 0; t < 4; ++t) rwa[t] = *(const unsigned long long*)(base + ida[t] * 16 + c8 * 2);
    #pragma unroll
    for (int t = 0; t < 4; ++t) rwb[t] = *(const unsigned long long*)(base + idb[t] * 16 + c8 * 2);
    float oa[4], ob[4];
    if constexpr (ON) {
        #pragma unroll
        for (int t = 0; t < 4; ++t) { oa[t] = onorm[ida[t]]; ob[t] = onorm[idb[t]]; }
    }
    #pragma unroll
    for (int t = 0; t < 4; ++t) {
        unsigned lo = (unsigned)rwa[t], hi = (unsigned)(rwa[t] >> 32);
        float s = ON ? oa[t] : 1.f;
        A[0] += s * u2f(lo << 16); A[1] += s * u2f(lo & 0xFFFF0000u);
        A[2] += s * u2f(hi << 16); A[3] += s * u2f(hi & 0xFFFF0000u);
    }
    #pragma unroll
    for (int t = 0; t < 4; ++t) {
        unsigned lo = (unsigned)rwb[t], hi = (unsigned)(rwb[t] >> 32);
        float s = ON ? ob[t] : 1.f;
        B[0] += s * u2f(lo << 16); B[1] += s * u2f(lo & 0xFFFF0000u);
        B[2] += s * u2f(hi << 16); B[3] += s * u2f(hi & 0xFFFF0000u);
    }
    int nqa = (na + 7) >> 3;
    #pragma unroll 1
    for (int t = 4; t < nqa; ++t) {          // rare: n > 32
        unsigned long long c = __builtin_nontemporal_load(&ea[2 * t + qi]);
        int ix = (t * 8 + g8 < na) ? (int)((c >> sh) & 0xFFFFu) : N_NODES;
        unsigned long long w = *(const unsigned long long*)(base + ix * 16 + c8 * 2);
        unsigned lo = (unsigned)w, hi = (unsigned)(w >> 32);
        float s = 1.f;
        if constexpr (ON) s = onorm[ix];
        A[0] += s * u2f(lo << 16); A[1] += s * u2f(lo & 0xFFFF0000u);
        A[2] += s * u2f(hi << 16); A[3] += s * u2f(hi & 0xFFFF0000u);
    }
    int nqb = (nb + 7) >> 3;
    #pragma unroll 1
    for (int t = 4; t < nqb; ++t) {
        unsigned long long c = __builtin_nontemporal_load(&eb[2 * t + qi]);
        int ix = (t * 8 + g8 < nb) ? (int)((c >> sh) & 0xFFFFu) : N_NODES;
        unsigned long long w = *(const unsigned long long*)(base + ix * 16 + c8 * 2);
        unsigned lo = (unsigned)w, hi = (unsigned)(w >> 32);
        float s = 1.f;
        if constexpr (ON) s = onorm[ix];
        B[0] += s * u2f(lo << 16); B[1] += s * u2f(lo & 0xFFFF0000u);
        B[2] += s * u2f(hi << 16); B[3] += s * u2f(hi & 0xFFFF0000u);
    }
    #pragma unroll
    for (int j = 0; j < 4; ++j) {    // fold 8 edge-slot groups
        A[j] += __shfl_xor(A[j], 8);  B[j] += __shfl_xor(B[j], 8);
        A[j] += __shfl_xor(A[j], 16); B[j] += __shfl_xor(B[j], 16);
        A[j] += __shfl_xor(A[j], 32); B[j] += __shfl_xor(B[j], 32);
    }
}

// ---------------------------------------------------------------- 4) gather1: feature-split, 2 nodes/wave
// Half h: H1h'[v][f] = onorm_v * relu(inorm_v * Σ onorm_u·A1h[u][f] + b1[f])
__global__ __launch_bounds__(256) void gather1_kernel(const int* __restrict__ ncnt,
                                                      const unsigned short* __restrict__ ebuf,
                                                      const unsigned short* __restrict__ A1lo,
                                                      const unsigned short* __restrict__ A1hi,
                                                      const float* __restrict__ onorm,
                                                      const float* __restrict__ inorm,
                                                      const float* __restrict__ b1,
                                                      unsigned short* __restrict__ H1lo,
                                                      unsigned short* __restrict__ H1hi,
                                                      float* __restrict__ out) {
    if (blockIdx.x == 0) {
        int t = threadIdx.x;
        for (int k = t; k < BATCH * 2; k += 256) out[k] = 0.f;
        if (t < 8) ((unsigned long long*)(H1lo + (size_t)N_NODES * 32))[t] = 0ull;
        else if (t < 16) ((unsigned long long*)(H1hi + (size_t)N_NODES * 32))[t - 8] = 0ull;
    }
    int lane = threadIdx.x & 63;
    int wu = __builtin_amdgcn_readfirstlane(threadIdx.x >> 6);
    int c8 = lane & 7, g8 = lane >> 3;
    int va = blockIdx.x * 8 + wu * 2;          // grid = N_NODES/8 = 7424, exact
    int vb = va + 1;
    int na = ncnt[va], nb = ncnt[vb];
    float ina = inorm[va], ona = onorm[va];
    float inb = inorm[vb], onb = onorm[vb];
    #pragma unroll
    for (int half = 0; half < 2; ++half) {
        const unsigned* base = (const unsigned*)(half ? A1hi : A1lo);
        unsigned short* H = half ? H1hi : H1lo;
        float4 b1q = ((const float4*)b1)[half * 8 + c8];
        float A[4] = {0.f,0.f,0.f,0.f}, B[4] = {0.f,0.f,0.f,0.f};
        gath2<true>(base, ebuf, onorm, va, vb, na, nb, c8, g8, A, B);
        float ha0 = fmaxf(ina * A[0] + b1q.x, 0.f) * ona;
        float ha1 = fmaxf(ina * A[1] + b1q.y, 0.f) * ona;
        float ha2 = fmaxf(ina * A[2] + b1q.z, 0.f) * ona;
        float ha3 = fmaxf(ina * A[3] + b1q.w, 0.f) * ona;
        float hb0 = fmaxf(inb * B[0] + b1q.x, 0.f) * onb;
        float hb1 = fmaxf(inb * B[1] + b1q.y, 0.f) * onb;
        float hb2 = fmaxf(inb * B[2] + b1q.z, 0.f) * onb;
        float hb3 = fmaxf(inb * B[3] + b1q.w, 0.f) * onb;
        if (g8 == 0) {
            unsigned lo = (unsigned)f2bf(ha0) | ((unsigned)f2bf(ha1) << 16);
            unsigned hi = (unsigned)f2bf(ha2) | ((unsigned)f2bf(ha3) << 16);
            __builtin_nontemporal_store(((unsigned long long)hi << 32) | lo,
                                        (unsigned long long*)H + (size_t)va * 8 + c8);
            lo = (unsigned)f2bf(hb0) | ((unsigned)f2bf(hb1) << 16);
            hi = (unsigned)f2bf(hb2) | ((unsigned)f2bf(hb3) << 16);
            __builtin_nontemporal_store(((unsigned long long)hi << 32) | lo,
                                        (unsigned long long*)H + (size_t)vb * 8 + c8);
        }
    }
}

// ---------------------------------------------------------------- 5) readout: feature-split gather2 + W2 matvec + Wc dot
__global__ __launch_bounds__(256) void readout_kernel(const int* __restrict__ ncnt,
                                                      const unsigned short* __restrict__ ebuf,
                                                      const unsigned short* __restrict__ H1lo,
                                                      const unsigned short* __restrict__ H1hi,
                                                      const float* __restrict__ inorm,
                                                      const float* __restrict__ b2,
                                                      const float* __restrict__ W2,
                                                      const float* __restrict__ Wc,
                                                      const float* __restrict__ bc,
                                                      float* __restrict__ out) {
    __shared__ float Gs[NPB][F_HID];   // 7424 B
    __shared__ float ls[8];
    int g = blockIdx.x >> 2, part = blockIdx.x & 3;
    int nbase = g * NPG + part * NPB;
    int lane = threadIdx.x & 63;
    int wu = __builtin_amdgcn_readfirstlane(threadIdx.x >> 6);
    int c8 = lane & 7, g8 = lane >> 3;
    // ---- phase 1: gather both halves (half-phases separated for L2 residency)
    #pragma unroll
    for (int half = 0; half < 2; ++half) {
        const unsigned* base = (const unsigned*)(half ? H1hi : H1lo);
        for (int nl = wu * 2; nl + 1 < NPB; nl += 8) {
            int va = nbase + nl, vb = va + 1;
            int na = ncnt[va], nb = ncnt[vb];
            float A[4] = {0.f,0.f,0.f,0.f}, B[4] = {0.f,0.f,0.f,0.f};
            gath2<false>(base, ebuf, (const float*)nullptr, va, vb, na, nb, c8, g8, A, B);
            if (g8 == 0) {
                float4 m4; m4.x = A[0]; m4.y = A[1]; m4.z = A[2]; m4.w = A[3];
                *(float4*)&Gs[nl][half * 32 + c8 * 4] = m4;
                m4.x = B[0]; m4.y = B[1]; m4.z = B[2]; m4.w = B[3];
                *(float4*)&Gs[nl + 1][half * 32 + c8 * 4] = m4;
            }
        }
        if (wu == 2) {   // leftover node 28
            int v = nbase + 28;
            int n = ncnt[v];
            float A[4] = {0.f,0.f,0.f,0.f}, D[4] = {0.f,0.f,0.f,0.f};
            gath2<false>(base, ebuf, (const float*)nullptr, v, v, n, 0, c8, g8, A, D);
            if (g8 == 0) {
                float4 m4; m4.x = A[0]; m4.y = A[1]; m4.z = A[2]; m4.w = A[3];
                *(float4*)&Gs[28][half * 32 + c8 * 4] = m4;
            }
        }
    }
    __syncthreads();
    // ---- phase 2: W2 matvec + activation + Wc dot
    float w2[F_HID];
    #pragma unroll
    for (int k = 0; k < F_HID; ++k) w2[k] = W2[k * F_HID + lane];
    float b2l = b2[lane];
    float s0 = 0.f, s1 = 0.f;
    for (int nl = wu; nl < NPB; nl += 4) {
        int v = nbase + nl;
        float acc = 0.f;
        #pragma unroll
        for (int k = 0; k < F_HID; k += 4) {
            float4 gk = *(const float4*)&Gs[nl][k];   // uniform addr: LDS broadcast
            acc += gk.x * w2[k] + gk.y * w2[k + 1] + gk.z * w2[k + 2] + gk.w * w2[k + 3];
        }
        float h = fmaxf(inorm[v] * acc + b2l, 0.f);
        float2 w = ((const float2*)Wc)[(part * NPB + nl) * F_HID + lane];
        s0 += h * w.x;
        s1 += h * w.y;
    }
    #pragma unroll
    for (int off = 32; off > 0; off >>= 1) {
        s0 += __shfl_down(s0, off);
        s1 += __shfl_down(s1, off);
    }
    if (lane == 0) { ls[wu * 2] = s0; ls[wu * 2 + 1] = s1; }
    __syncthreads();
    if (threadIdx.x < 2) {
        float t = 0.f;
        #pragma unroll
        for (int w = 0; w < 4; ++w) t += ls[w * 2 + threadIdx.x];
        if (part == 0) t += bc[threadIdx.x];
        atomicAdd(&out[g * 2 + threadIdx.x], t);
    }
}

extern "C" void kernel_launch(void* const* d_in, const int* in_sizes, int n_in,
                              void* d_out, int out_size, void* d_ws, size_t ws_size,
                              hipStream_t stream) {
    const float* feat = (const float*)d_in[0];
    const int*   src  = (const int*)d_in[1];
    const int*   dst  = (const int*)d_in[2];
    // d_in[3] = batch_size (fixed 512)
    const float* W1 = (const float*)d_in[4];
    const float* b1 = (const float*)d_in[5];
    const float* W2 = (const float*)d_in[6];
    const float* b2 = (const float*)d_in[7];
    const float* Wc = (const float*)d_in[8];
    const float* bc = (const float*)d_in[9];
    float* out = (float*)d_out;

    // ws layout (≈42.5 MB):
    // cnt2 u16[NSLD*N] (19MB) | cnt2s u16[NSLS*N] (7.6MB) | onorm f32[N+1] | inorm f32[N]
    // | ncnt i32[N] | ebuf u16[N*CCAP] | A1lo bf16[(N+1)*32] | A1hi bf16[(N+1)*32]
    // H1lo/H1hi (bf16[(N+1)*32] each) ALIAS cnt2 (dead after place).
    unsigned short* cnt2  = (unsigned short*)d_ws;
    unsigned short* cnt2s = cnt2 + (size_t)NSLD * N_NODES;
    float* onorm = (float*)(cnt2s + (size_t)NSLS * N_NODES);
    float* inorm = onorm + N_NODES + 1;
    int* ncnt    = (int*)(inorm + N_NODES);
    unsigned short* ebuf = (unsigned short*)(ncnt + N_NODES);
    unsigned short* A1lo = ebuf + (size_t)N_NODES * CCAP;
    unsigned short* A1hi = A1lo + (size_t)(N_NODES + 1) * 32;
    unsigned short* H1lo = cnt2;                               // alias
    unsigned short* H1hi = H1lo + (size_t)(N_NODES + 1) * 32;  // alias

    hist_kernel<<<NSLD * NR + NSLS * NR, 256, 0, stream>>>(src, dst, cnt2, cnt2s);
    scan_gemm1_kernel<<<SCAN_BLK + GEMM_BLK, 256, 0, stream>>>(cnt2, cnt2s, onorm, inorm,
                                                               ncnt, feat, W1, A1lo, A1hi);
    place_kernel<<<NSLD * NR, 256, 0, stream>>>(src, dst, cnt2, ebuf);
    gather1_kernel<<<N_NODES / 8, 256, 0, stream>>>(ncnt, ebuf, A1lo, A1hi, onorm, inorm,
                                                    b1, H1lo, H1hi, out);
    readout_kernel<<<BATCH * GPB, 256, 0, stream>>>(ncnt, ebuf, H1lo, H1hi, inorm, b2,
                                                    W2, Wc, bc, out);
}

// Round 16
// 223.514 us; speedup vs baseline: 1.1481x; 1.1481x over previous
//
#include <hip/hip_runtime.h>

#define N_NODES 59392
#define N_EDGES 1187840
#define F_IN 116
#define F_HID 64
#define BATCH 512
#define NPG 116              // nodes per graph
#define CCAP 64              // bucket: 64 u16 = one 128B line/node; P(indeg>64)~1e-15, guarded
#define NSLD 160             // dst-hist / place slices
#define EPSD (N_EDGES / NSLD)  // 7424 edges per dst-slice (exact)
#define NSLS 64              // src-hist slices
#define EPSS (N_EDGES / NSLS)  // 18560 edges per src-slice (exact)
#define NR 4                 // node ranges
#define NPR4 (N_NODES / NR)  // 14848 nodes per range (exact)
#define GPB 4                // readout blocks per graph
#define NPB (NPG / GPB)      // 29 nodes per readout block (exact)
#define SCAN_BLK (N_NODES / 256)   // 232
#define GEMM_BLK 640

typedef __attribute__((ext_vector_type(8))) short short8;
typedef __attribute__((ext_vector_type(4))) float float4v;

__device__ __forceinline__ float u2f(unsigned u) {
    union { unsigned u; float f; } x; x.u = u; return x.f;
}
__device__ __forceinline__ float bf2f(unsigned short h) {
    union { unsigned u; float f; } x; x.u = (unsigned)h << 16; return x.f;
}
__device__ __forceinline__ unsigned short f2bf(float f) {
    union { float f; unsigned u; } x; x.f = f;
    unsigned r = x.u + 0x7FFF + ((x.u >> 16) & 1);   // RNE
    return (unsigned short)(r >> 16);
}

// ---------------------------------------------------------------- 1) histograms: 896 blocks, 29.7KB packed-u16 LDS bins
__global__ __launch_bounds__(256) void hist_kernel(const int* __restrict__ src,
                                                   const int* __restrict__ dst,
                                                   unsigned short* __restrict__ cnt2,
                                                   unsigned short* __restrict__ cnt2s) {
    __shared__ unsigned bins[NPR4 / 2];   // 29696 B
    int tid = threadIdx.x;
    int b = blockIdx.x;
    const int* __restrict__ idx;
    unsigned short* outp;
    int slice, range, nedge;
    if (b < NSLD * NR) {
        slice = b >> 2; range = b & 3; idx = dst; outp = cnt2; nedge = EPSD;
    } else {
        int bb = b - NSLD * NR;
        slice = bb >> 2; range = bb & 3; idx = src; outp = cnt2s; nedge = EPSS;
    }
    int r0 = range * NPR4;
    long ebase = (long)slice * nedge;
    for (int k = tid; k < NPR4 / 2; k += 256) bins[k] = 0;
    __syncthreads();
    for (int k = tid; k < nedge; k += 256) {
        int v = idx[ebase + k] - r0;
        if ((unsigned)v < NPR4) atomicAdd(&bins[v >> 1], 1u << ((v & 1) * 16));
    }
    __syncthreads();
    unsigned* op = (unsigned*)(outp + (size_t)slice * N_NODES + r0);
    for (int k = tid; k < NPR4 / 2; k += 256) op[k] = bins[k];
}

// ---------------------------------------------------------------- 2) FUSED: scan+norms (blocks 0..231) | gemm1 MFMA (blocks 232..871)
__global__ __launch_bounds__(256) void scan_gemm1_kernel(unsigned short* __restrict__ cnt2,
                                                         const unsigned short* __restrict__ cnt2s,
                                                         float* __restrict__ onorm,
                                                         float* __restrict__ inorm,
                                                         int* __restrict__ ncnt,
                                                         const float* __restrict__ feat,
                                                         const float* __restrict__ W1,
                                                         unsigned short* __restrict__ A1h) {
    if (blockIdx.x < SCAN_BLK) {
        // ---- scan role: 8-wide batched loads (MLP on the 160-deep chain)
        int d = blockIdx.x * 256 + threadIdx.x;
        int run = 0;
        #pragma unroll 1
        for (int i = 0; i < NSLD; i += 8) {
            int c[8];
            #pragma unroll
            for (int j = 0; j < 8; ++j) c[j] = cnt2[(size_t)(i + j) * N_NODES + d];
            #pragma unroll
            for (int j = 0; j < 8; ++j) {
                cnt2[(size_t)(i + j) * N_NODES + d] = (unsigned short)run;
                run += c[j];
            }
        }
        int o = 0;
        #pragma unroll 1
        for (int i = 0; i < NSLS; i += 8) {
            int c[8];
            #pragma unroll
            for (int j = 0; j < 8; ++j) c[j] = cnt2s[(size_t)(i + j) * N_NODES + d];
            #pragma unroll
            for (int j = 0; j < 8; ++j) o += c[j];
        }
        onorm[d] = rsqrtf(fmaxf((float)o, 1.0f));
        inorm[d] = rsqrtf(fmaxf((float)run, 1.0f));
        ncnt[d] = run < CCAP ? run : CCAP;
        if (d == 0) onorm[N_NODES] = 0.f;         // zero-row kill switch
        return;
    }
    // ---- gemm1 role: A1 = feat @ W1 (bf16 out, hi/lo split = fp32-exact)
    int lane = threadIdx.x & 63;
    int c16 = lane & 15, quad = lane >> 4;
    short8 Bhi[4][4], Blo[4][4];
    #pragma unroll
    for (int kiter = 0; kiter < 4; ++kiter) {
        #pragma unroll
        for (int t = 0; t < 4; ++t) {
            #pragma unroll
            for (int j = 0; j < 8; ++j) {
                int k = kiter * 32 + quad * 8 + j;
                float w = (k < F_IN) ? W1[k * F_HID + t * 16 + c16] : 0.f;
                unsigned short hi = f2bf(w);
                unsigned short lo = f2bf(w - bf2f(hi));
                Bhi[kiter][t][j] = (short)hi;
                Blo[kiter][t][j] = (short)lo;
            }
        }
    }
    int bid = blockIdx.x - SCAN_BLK;
    int wid = (bid * 256 + threadIdx.x) >> 6;
    int nwaves = (GEMM_BLK * 256) >> 6;
    const int ntiles = N_NODES / 16;   // 3712
    for (int tile = wid; tile < ntiles; tile += nwaves) {
        int base = tile * 16;
        int row = base + c16;
        const float* fp = feat + (size_t)row * F_IN;
        float4v acc[4] = {{0.f,0.f,0.f,0.f},{0.f,0.f,0.f,0.f},{0.f,0.f,0.f,0.f},{0.f,0.f,0.f,0.f}};
        #pragma unroll
        for (int kiter = 0; kiter < 4; ++kiter) {
            int koff = kiter * 32 + quad * 8;
            float f[8];
            if (koff + 8 <= F_IN) {
                float4 x = *(const float4*)(fp + koff);
                float4 y = *(const float4*)(fp + koff + 4);
                f[0]=x.x; f[1]=x.y; f[2]=x.z; f[3]=x.w;
                f[4]=y.x; f[5]=y.y; f[6]=y.z; f[7]=y.w;
            } else {
                #pragma unroll
                for (int j = 0; j < 8; ++j) f[j] = (koff + j < F_IN) ? fp[koff + j] : 0.f;
            }
            short8 ah, al;
            #pragma unroll
            for (int j = 0; j < 8; ++j) {
                float v = f[j];
                unsigned short hi = f2bf(v);
                ah[j] = (short)hi;
                al[j] = (short)f2bf(v - bf2f(hi));
            }
            #pragma unroll
            for (int t = 0; t < 4; ++t) {
                acc[t] = __builtin_amdgcn_mfma_f32_16x16x32_bf16(ah, Bhi[kiter][t], acc[t], 0, 0, 0);
                acc[t] = __builtin_amdgcn_mfma_f32_16x16x32_bf16(al, Bhi[kiter][t], acc[t], 0, 0, 0);
                acc[t] = __builtin_amdgcn_mfma_f32_16x16x32_bf16(ah, Blo[kiter][t], acc[t], 0, 0, 0);
            }
        }
        #pragma unroll
        for (int t = 0; t < 4; ++t) {
            #pragma unroll
            for (int r = 0; r < 4; ++r) {
                int node = base + quad * 4 + r;
                A1h[(size_t)node * F_HID + t * 16 + c16] = f2bf(acc[t][r]);
            }
        }
    }
}

// ---------------------------------------------------------------- 3) placement: 640 blocks, packed cursors, unroll-4
__global__ __launch_bounds__(256) void place_kernel(const int* __restrict__ src,
                                                    const int* __restrict__ dst,
                                                    const unsigned short* __restrict__ cnt2,
                                                    unsigned short* __restrict__ ebuf) {
    __shared__ unsigned cur[NPR4 / 2];    // 29696 B
    int tid = threadIdx.x;
    int slice = blockIdx.x >> 2;
    int r0 = (blockIdx.x & 3) * NPR4;
    long ebase = (long)slice * EPSD;
    const unsigned* pp = (const unsigned*)(cnt2 + (size_t)slice * N_NODES + r0);
    for (int k = tid; k < NPR4 / 2; k += 256) cur[k] = pp[k];
    __syncthreads();
    #pragma unroll 1
    for (int t = 0; t < 7; ++t) {
        int k = t * 1024 + tid;
        int d0 = dst[ebase + k],        s0 = src[ebase + k];
        int d1 = dst[ebase + k + 256],  s1 = src[ebase + k + 256];
        int d2 = dst[ebase + k + 512],  s2 = src[ebase + k + 512];
        int d3 = dst[ebase + k + 768],  s3 = src[ebase + k + 768];
        #define PLACE1(dd, ss)                                                    \
            { int dr = (dd) - r0;                                                 \
              if ((unsigned)dr < NPR4) {                                          \
                  int sh = (dr & 1) * 16;                                         \
                  unsigned old = atomicAdd(&cur[dr >> 1], 1u << sh);              \
                  unsigned pos = (old >> sh) & 0xFFFFu;                           \
                  if (pos < CCAP) ebuf[(size_t)(dd) * CCAP + pos] = (unsigned short)(ss); } }
        PLACE1(d0, s0) PLACE1(d1, s1) PLACE1(d2, s2) PLACE1(d3, s3)
    }
    {   // tail: edges [7168, 7424)
        int k = 7168 + tid;
        int d0 = dst[ebase + k], s0 = src[ebase + k];
        PLACE1(d0, s0)
        #undef PLACE1
    }
}

// ---------------------------------------------------------------- gather core: TWO nodes per wave, 16 independent 128B row loads
// Full-row layout (row = one cache line — optimal at 128B line granularity).
// Index/bucket loads NONTEMPORAL (streamed once; don't evict row lines).
// Invalid slots -> row N_NODES (onorm=0 / zeroed row).
template<bool ON>
__device__ __forceinline__ void gather2n(const unsigned* __restrict__ base,
                                         const unsigned short* __restrict__ ebuf,
                                         const float* __restrict__ onorm,
                                         int va, int vb, int na, int nb,
                                         int c16, int g4, int sh16,
                                         float& a0, float& a1, float& a2, float& a3,
                                         float& b0, float& b1, float& b2, float& b3) {
    const unsigned long long* ea = (const unsigned long long*)(ebuf + (size_t)va * CCAP);
    const unsigned long long* eb = (const unsigned long long*)(ebuf + (size_t)vb * CCAP);
    unsigned long long cha[8], chb[8];
    #pragma unroll
    for (int t = 0; t < 8; ++t) cha[t] = __builtin_nontemporal_load(&ea[t]);
    #pragma unroll
    for (int t = 0; t < 8; ++t) chb[t] = __builtin_nontemporal_load(&eb[t]);
    int ida[8], idb[8];
    #pragma unroll
    for (int t = 0; t < 8; ++t) {
        ida[t] = (t * 4 + g4 < na) ? (int)((cha[t] >> sh16) & 0xFFFFu) : N_NODES;
        idb[t] = (t * 4 + g4 < nb) ? (int)((chb[t] >> sh16) & 0xFFFFu) : N_NODES;
    }
    unsigned long long rwa[8], rwb[8];
    #pragma unroll
    for (int t = 0; t < 8; ++t) rwa[t] = *(const unsigned long long*)(base + ida[t] * 32 + c16 * 2);
    #pragma unroll
    for (int t = 0; t < 8; ++t) rwb[t] = *(const unsigned long long*)(base + idb[t] * 32 + c16 * 2);
    float oa[8], ob[8];
    if constexpr (ON) {
        #pragma unroll
        for (int t = 0; t < 8; ++t) { oa[t] = onorm[ida[t]]; ob[t] = onorm[idb[t]]; }
    }
    #pragma unroll
    for (int t = 0; t < 8; ++t) {
        unsigned lo = (unsigned)rwa[t], hi = (unsigned)(rwa[t] >> 32);
        float s = ON ? oa[t] : 1.f;
        a0 += s * u2f(lo << 16); a1 += s * u2f(lo & 0xFFFF0000u);
        a2 += s * u2f(hi << 16); a3 += s * u2f(hi & 0xFFFF0000u);
    }
    #pragma unroll
    for (int t = 0; t < 8; ++t) {
        unsigned lo = (unsigned)rwb[t], hi = (unsigned)(rwb[t] >> 32);
        float s = ON ? ob[t] : 1.f;
        b0 += s * u2f(lo << 16); b1 += s * u2f(lo & 0xFFFF0000u);
        b2 += s * u2f(hi << 16); b3 += s * u2f(hi & 0xFFFF0000u);
    }
    int nqa = (na + 3) >> 2;
    #pragma unroll 1
    for (int t = 8; t < nqa; ++t) {          // rare: n > 32
        unsigned long long c = __builtin_nontemporal_load(&ea[t]);
        int e = t * 4 + g4;
        int ix = (e < na) ? (int)((c >> sh16) & 0xFFFFu) : N_NODES;
        unsigned long long w = *(const unsigned long long*)(base + ix * 32 + c16 * 2);
        unsigned lo = (unsigned)w, hi = (unsigned)(w >> 32);
        float s = 1.f;
        if constexpr (ON) s = onorm[ix];
        a0 += s * u2f(lo << 16); a1 += s * u2f(lo & 0xFFFF0000u);
        a2 += s * u2f(hi << 16); a3 += s * u2f(hi & 0xFFFF0000u);
    }
    int nqb = (nb + 3) >> 2;
    #pragma unroll 1
    for (int t = 8; t < nqb; ++t) {
        unsigned long long c = __builtin_nontemporal_load(&eb[t]);
        int e = t * 4 + g4;
        int ix = (e < nb) ? (int)((c >> sh16) & 0xFFFFu) : N_NODES;
        unsigned long long w = *(const unsigned long long*)(base + ix * 32 + c16 * 2);
        unsigned lo = (unsigned)w, hi = (unsigned)(w >> 32);
        float s = 1.f;
        if constexpr (ON) s = onorm[ix];
        b0 += s * u2f(lo << 16); b1 += s * u2f(lo & 0xFFFF0000u);
        b2 += s * u2f(hi << 16); b3 += s * u2f(hi & 0xFFFF0000u);
    }
    a0 += __shfl_xor(a0, 16); a1 += __shfl_xor(a1, 16);
    a2 += __shfl_xor(a2, 16); a3 += __shfl_xor(a3, 16);
    a0 += __shfl_xor(a0, 32); a1 += __shfl_xor(a1, 32);
    a2 += __shfl_xor(a2, 32); a3 += __shfl_xor(a3, 32);
    b0 += __shfl_xor(b0, 16); b1 += __shfl_xor(b1, 16);
    b2 += __shfl_xor(b2, 16); b3 += __shfl_xor(b3, 16);
    b0 += __shfl_xor(b0, 32); b1 += __shfl_xor(b1, 32);
    b2 += __shfl_xor(b2, 32); b3 += __shfl_xor(b3, 32);
}

// ---------------------------------------------------------------- 4) gather1: 2 nodes/wave; H1' = onorm_v ⊙ relu(inorm_v ⊙ Σ onorm_u·A1[u] + b1)
__global__ __launch_bounds__(256) void gather1_kernel(const int* __restrict__ ncnt,
                                                      const unsigned short* __restrict__ ebuf,
                                                      const unsigned short* __restrict__ A1h,
                                                      const float* __restrict__ onorm,
                                                      const float* __restrict__ inorm,
                                                      const float* __restrict__ b1,
                                                      unsigned short* __restrict__ H1h,
                                                      float* __restrict__ out) {
    if (blockIdx.x == 0) {
        int t = threadIdx.x;
        for (int k = t; k < BATCH * 2; k += 256) out[k] = 0.f;
        if (t < 16) ((unsigned long long*)(H1h + (size_t)N_NODES * F_HID))[t] = 0ull;
    }
    int lane = threadIdx.x & 63;
    int wu = __builtin_amdgcn_readfirstlane(threadIdx.x >> 6);   // uniform wave id
    int c16 = lane & 15, g4 = lane >> 4, sh16 = g4 * 16;
    int va = blockIdx.x * 8 + wu * 2;          // grid = N_NODES/8 = 7424, exact
    int vb = va + 1;
    int na = ncnt[va], nb = ncnt[vb];          // uniform -> scalar loads
    const unsigned* base = (const unsigned*)A1h;
    float4 b1q = ((const float4*)b1)[c16];
    float a0 = 0.f, a1 = 0.f, a2 = 0.f, a3 = 0.f;
    float b0 = 0.f, b1v = 0.f, b2v = 0.f, b3 = 0.f;
    gather2n<true>(base, ebuf, onorm, va, vb, na, nb, c16, g4, sh16,
                   a0, a1, a2, a3, b0, b1v, b2v, b3);
    float ina = inorm[va], ona = onorm[va];
    float inb = inorm[vb], onb = onorm[vb];
    float ha0 = fmaxf(ina * a0 + b1q.x, 0.f) * ona;
    float ha1 = fmaxf(ina * a1 + b1q.y, 0.f) * ona;
    float ha2 = fmaxf(ina * a2 + b1q.z, 0.f) * ona;
    float ha3 = fmaxf(ina * a3 + b1q.w, 0.f) * ona;
    float hb0 = fmaxf(inb * b0 + b1q.x, 0.f) * onb;
    float hb1 = fmaxf(inb * b1v + b1q.y, 0.f) * onb;
    float hb2 = fmaxf(inb * b2v + b1q.z, 0.f) * onb;
    float hb3 = fmaxf(inb * b3 + b1q.w, 0.f) * onb;
    if (g4 == 0) {
        unsigned lo = (unsigned)f2bf(ha0) | ((unsigned)f2bf(ha1) << 16);
        unsigned hi = (unsigned)f2bf(ha2) | ((unsigned)f2bf(ha3) << 16);
        ((unsigned long long*)H1h)[(size_t)va * 16 + c16] = ((unsigned long long)hi << 32) | lo;
        lo = (unsigned)f2bf(hb0) | ((unsigned)f2bf(hb1) << 16);
        hi = (unsigned)f2bf(hb2) | ((unsigned)f2bf(hb3) << 16);
        ((unsigned long long*)H1h)[(size_t)vb * 16 + c16] = ((unsigned long long)hi << 32) | lo;
    }
}

// ---------------------------------------------------------------- 5) readout: 4 blocks/graph, 2-node gather pairs
__global__ __launch_bounds__(256) void readout_kernel(const int* __restrict__ ncnt,
                                                      const unsigned short* __restrict__ ebuf,
                                                      const unsigned short* __restrict__ H1h,
                                                      const float* __restrict__ inorm,
                                                      const float* __restrict__ b2,
                                                      const float* __restrict__ W2,
                                                      const float* __restrict__ Wc,
                                                      const float* __restrict__ bc,
                                                      float* __restrict__ out) {
    __shared__ float Gs[NPB][F_HID];   // 7424 B
    __shared__ float ls[8];
    int g = blockIdx.x >> 2, part = blockIdx.x & 3;
    int nbase = g * NPG + part * NPB;
    int lane = threadIdx.x & 63;
    int wu = __builtin_amdgcn_readfirstlane(threadIdx.x >> 6);
    int c16 = lane & 15, g4 = lane >> 4, sh16 = g4 * 16;
    const unsigned* base = (const unsigned*)H1h;
    // ---- phase 1: gather pairs (waves cover nodes 0..27; node 28 by wave 2)
    for (int nl = wu * 2; nl + 1 < NPB; nl += 8) {
        int va = nbase + nl, vb = va + 1;
        int na = ncnt[va], nb = ncnt[vb];
        float a0 = 0.f, a1 = 0.f, a2 = 0.f, a3 = 0.f;
        float b0 = 0.f, b1 = 0.f, b2v = 0.f, b3 = 0.f;
        gather2n<false>(base, ebuf, (const float*)nullptr, va, vb, na, nb, c16, g4, sh16,
                        a0, a1, a2, a3, b0, b1, b2v, b3);
        if (g4 == 0) {
            float4 m4; m4.x = a0; m4.y = a1; m4.z = a2; m4.w = a3;
            *(float4*)&Gs[nl][c16 * 4] = m4;
            m4.x = b0; m4.y = b1; m4.z = b2v; m4.w = b3;
            *(float4*)&Gs[nl + 1][c16 * 4] = m4;
        }
    }
    if (wu == 2) {   // leftover node 28
        int v = nbase + 28;
        int n = ncnt[v];
        float a0 = 0.f, a1 = 0.f, a2 = 0.f, a3 = 0.f;
        float d0 = 0.f, d1 = 0.f, d2 = 0.f, d3 = 0.f;
        gather2n<false>(base, ebuf, (const float*)nullptr, v, v, n, 0, c16, g4, sh16,
                        a0, a1, a2, a3, d0, d1, d2, d3);
        if (g4 == 0) {
            float4 m4; m4.x = a0; m4.y = a1; m4.z = a2; m4.w = a3;
            *(float4*)&Gs[28][c16 * 4] = m4;
        }
    }
    __syncthreads();
    // ---- phase 2: W2 matvec + activation + Wc dot
    float w2[F_HID];
    #pragma unroll
    for (int k = 0; k < F_HID; ++k) w2[k] = W2[k * F_HID + lane];
    float b2l = b2[lane];
    float s0 = 0.f, s1 = 0.f;
    for (int nl = wu; nl < NPB; nl += 4) {
        int v = nbase + nl;
        float acc = 0.f;
        #pragma unroll
        for (int k = 0; k < F_HID; k += 4) {
            float4 gk = *(const float4*)&Gs[nl][k];   // uniform addr: LDS broadcast
            acc += gk.x * w2[k] + gk.y * w2[k + 1] + gk.z * w2[k + 2] + gk.w * w2[k + 3];
        }
        float h = fmaxf(inorm[v] * acc + b2l, 0.f);
        float2 w = ((const float2*)Wc)[(part * NPB + nl) * F_HID + lane];
        s0 += h * w.x;
        s1 += h * w.y;
    }
    #pragma unroll
    for (int off = 32; off > 0; off >>= 1) {
        s0 += __shfl_down(s0, off);
        s1 += __shfl_down(s1, off);
    }
    if (lane == 0) { ls[wu * 2] = s0; ls[wu * 2 + 1] = s1; }
    __syncthreads();
    if (threadIdx.x < 2) {
        float t = 0.f;
        #pragma unroll
        for (int w = 0; w < 4; ++w) t += ls[w * 2 + threadIdx.x];
        if (part == 0) t += bc[threadIdx.x];
        atomicAdd(&out[g * 2 + threadIdx.x], t);
    }
}

extern "C" void kernel_launch(void* const* d_in, const int* in_sizes, int n_in,
                              void* d_out, int out_size, void* d_ws, size_t ws_size,
                              hipStream_t stream) {
    const float* feat = (const float*)d_in[0];
    const int*   src  = (const int*)d_in[1];
    const int*   dst  = (const int*)d_in[2];
    // d_in[3] = batch_size (fixed 512)
    const float* W1 = (const float*)d_in[4];
    const float* b1 = (const float*)d_in[5];
    const float* W2 = (const float*)d_in[6];
    const float* b2 = (const float*)d_in[7];
    const float* Wc = (const float*)d_in[8];
    const float* bc = (const float*)d_in[9];
    float* out = (float*)d_out;

    // ws layout (≈42.5 MB):
    // cnt2 u16[NSLD*N] (19MB) | cnt2s u16[NSLS*N] (7.6MB) | onorm f32[N+1] | inorm f32[N]
    // | ncnt i32[N] | ebuf u16[N*CCAP] | A1h bf16[(N+1)*64]
    // H1h (bf16[(N+1)*64]) ALIASES cnt2 (dead after place; first written in gather1).
    unsigned short* cnt2  = (unsigned short*)d_ws;
    unsigned short* cnt2s = cnt2 + (size_t)NSLD * N_NODES;
    float* onorm = (float*)(cnt2s + (size_t)NSLS * N_NODES);
    float* inorm = onorm + N_NODES + 1;
    int* ncnt    = (int*)(inorm + N_NODES);
    unsigned short* ebuf = (unsigned short*)(ncnt + N_NODES);
    unsigned short* A1h  = ebuf + (size_t)N_NODES * CCAP;
    unsigned short* H1h  = cnt2;   // alias

    hist_kernel<<<NSLD * NR + NSLS * NR, 256, 0, stream>>>(src, dst, cnt2, cnt2s);
    scan_gemm1_kernel<<<SCAN_BLK + GEMM_BLK, 256, 0, stream>>>(cnt2, cnt2s, onorm, inorm,
                                                               ncnt, feat, W1, A1h);
    place_kernel<<<NSLD * NR, 256, 0, stream>>>(src, dst, cnt2, ebuf);
    gather1_kernel<<<N_NODES / 8, 256, 0, stream>>>(ncnt, ebuf, A1h, onorm, inorm, b1, H1h, out);
    readout_kernel<<<BATCH * GPB, 256, 0, stream>>>(ncnt, ebuf, H1h, inorm, b2, W2, Wc, bc, out);
}